// Round 1
// 1505.604 us; speedup vs baseline: 1.1749x; 1.1749x over previous
//
#include <hip/hip_runtime.h>

// Shapes fixed by the reference: H=4, D=128, S=8, dh=32.
#define NODE_F 1024                     // 8*128 elems per node

typedef short bf16x8 __attribute__((ext_vector_type(8)));
typedef float f32x4  __attribute__((ext_vector_type(4)));

__device__ inline ushort f2bf(float f) {
  union { float f; unsigned u; } v; v.f = f;
  unsigned r = v.u + 0x7FFFu + ((v.u >> 16) & 1u);   // RNE
  return (ushort)(r >> 16);
}
__device__ inline float bf2f(ushort u) {
  union { unsigned u; float f; } v; v.u = ((unsigned)u) << 16;
  return v.f;
}
// packed-pair bf16 -> f32 (low / high halves of a dword)
__device__ inline float blo(unsigned w) {
  union { unsigned u; float f; } v; v.u = w << 16; return v.f;
}
__device__ inline float bhi(unsigned w) {
  union { unsigned u; float f; } v; v.u = w & 0xFFFF0000u; return v.f;
}

struct RelW { const float *Win, *bin, *Wb, *bb, *Wo, *bo; };

// ---------------------------------------------------------------------------
// Weight prep. Mats 0..4 (Q,Ki,Vi,KB,VB; Wb composed into KB/VB; 1/sqrt(dh)
// folded into Q) are stored as bf16 in EXACT mfma_16x16x32 A-operand fragment
// order so gemm_mfma loads them with zero shuffling:
//   A'[o][k]: lane = quad*16 + (o&15), k = ks*32 + quad*8 + j
//   index = (((mat*4+ks)*8 + (o>>4))*64 + lane)*8 + j
// Mat 5 (Wo) stays fp32 transposed [k][o] for the fp32 finalize GEMM.
// ---------------------------------------------------------------------------
__global__ __launch_bounds__(128) void prep_weights(RelW r0, RelW r1, RelW r2,
    ushort* __restrict__ Wfrag, float* __restrict__ WoT,
    float* __restrict__ biasQKV, float* __restrict__ biasO)
{
  const int rel = blockIdx.z;
  RelW R = (rel == 0) ? r0 : (rel == 1 ? r1 : r2);
  const int o = blockIdx.x, m = blockIdx.y, k = threadIdx.x;
  const float scale = 0.17677669529663687f;   // 1/sqrt(32)
  float val;
  if (m == 0)      val = R.Win[o*128 + k] * scale;
  else if (m == 1) val = R.Win[(128+o)*128 + k];
  else if (m == 2) val = R.Win[(256+o)*128 + k];
  else if (m == 5) val = R.Wo[o*128 + k];
  else {
    const float* wr = R.Win + (m == 3 ? (128+o)*128 : (256+o)*128);
    float acc = 0.f;
    for (int i = 0; i < 128; ++i) acc += wr[i] * R.Wb[i*128 + k];
    val = acc;
  }
  if (m < 5) {
    const int ks = k >> 5, quad = (k >> 3) & 3, j = k & 7;
    const int ot = o >> 4, lane = quad * 16 + (o & 15);
    Wfrag[(size_t)rel*5*16384 + ((((m*4 + ks)*8 + ot)*64 + lane)*8 + j)] = f2bf(val);
  } else {
    WoT[(size_t)rel*16384 + k*128 + o] = val;
  }
  if (k == 0) {
    float bv;
    if (m == 0)      bv = R.bin[o] * scale;
    else if (m == 1) bv = R.bin[128+o];
    else if (m == 2) bv = R.bin[256+o];
    else if (m == 5) bv = R.bo[o];
    else {
      const float* wr = R.Win + (m == 3 ? (128+o)*128 : (256+o)*128);
      float acc = (m == 3) ? R.bin[128+o] : R.bin[256+o];
      for (int i = 0; i < 128; ++i) acc += wr[i] * R.bb[i];
      bv = acc;
    }
    if (m < 5) biasQKV[rel*640 + m*128 + o] = bv;
    else       biasO[rel*128 + o] = bv;
  }
}

// fp32 -> bf16 copies of x_a / x_b
__global__ __launch_bounds__(256) void conv_bf16(const float* __restrict__ xa,
    const float* __restrict__ xb, ushort* __restrict__ oa, ushort* __restrict__ ob)
{
  const float* x = blockIdx.y ? xb : xa;
  ushort* o = blockIdx.y ? ob : oa;
  const long i = ((long)blockIdx.x * 256 + threadIdx.x) * 4;
  float4 v = *(const float4*)&x[i];
  ushort4 r; r.x = f2bf(v.x); r.y = f2bf(v.y); r.z = f2bf(v.z); r.w = f2bf(v.w);
  *(ushort4*)&o[i] = r;
}

// --------------------------- CSR build (per relation) -----------------------
__global__ __launch_bounds__(256) void hist_edges(
    const int* __restrict__ e1, const int* __restrict__ e2, const int* __restrict__ e3,
    int* __restrict__ counts, int E, int N)
{
  const int r = blockIdx.y;
  const int* ei = (r == 0) ? e1 : (r == 1) ? e2 : e3;
  const int e = blockIdx.x * 256 + threadIdx.x;
  if (e < E) atomicAdd(&counts[(size_t)r * N + ei[E + e]], 1);
}

__global__ __launch_bounds__(1024) void scan_offsets(
    const int* __restrict__ counts, int* __restrict__ off,
    int* __restrict__ fill, int N)
{
  const int r = blockIdx.x;
  const int* cnt = counts + (size_t)r * N;
  int* offr  = off  + (size_t)r * (N + 1);
  int* fillr = fill + (size_t)r * N;
  __shared__ int buf[1024];
  __shared__ int carry;
  const int t = threadIdx.x;
  if (t == 0) carry = 0;
  __syncthreads();
  for (int base = 0; base < N; base += 1024) {
    const int idx = base + t;
    int v = (idx < N) ? cnt[idx] : 0;
    buf[t] = v;
    __syncthreads();
    for (int s = 1; s < 1024; s <<= 1) {
      int add = (t >= s) ? buf[t - s] : 0;
      __syncthreads();
      buf[t] += add;
      __syncthreads();
    }
    const int incl = buf[t];
    const int c = carry;
    if (idx < N) { offr[idx] = c + incl - v; fillr[idx] = c + incl - v; }
    __syncthreads();
    if (t == 1023) carry = c + incl;
    __syncthreads();
  }
  if (t == 0) offr[N] = carry;
}

__global__ __launch_bounds__(256) void scatter_edges(
    const int* __restrict__ e1, const int* __restrict__ e2, const int* __restrict__ e3,
    int* __restrict__ fill, int* __restrict__ esrc, int E, int N)
{
  const int r = blockIdx.y;
  const int* ei = (r == 0) ? e1 : (r == 1) ? e2 : e3;
  const int e = blockIdx.x * 256 + threadIdx.x;
  if (e < E) {
    const int d = ei[E + e], s = ei[e];
    const int pos = atomicAdd(&fill[(size_t)r * N + d], 1);
    esrc[(size_t)r * E + pos] = s;
  }
}

// ---------------------------------------------------------------------------
// MFMA projection GEMM. Block = 128 rows x 128 cols (= one mat; mat =
// blockIdx.y), 4 waves in a 2x2 wave grid, each wave 4x4 tiles of 16x16.
// Operand trick: A = pre-swizzled W fragments (M-index = output feature o),
// B = X rows (N-index = node row m)  =>  D[o][m] with D col(lane&15) = m,
// row(quad*4+reg) = o, so each lane packs 4 consecutive o as one 8B bf16x4
// store. No LDS anywhere.
// ---------------------------------------------------------------------------
__global__ __launch_bounds__(256) void gemm_mfma(
    const ushort* __restrict__ X16, const ushort* __restrict__ Wfrag,
    const float* __restrict__ biasQKV, ushort* __restrict__ Out, long matStride)
{
  const int mat = blockIdx.y;
  const long m0 = (long)blockIdx.x * 128;
  const int t = threadIdx.x, wave = t >> 6, lane = t & 63;
  const int wm = (wave & 1) * 64, wo = (wave >> 1) * 64;
  const int lrow = lane & 15, quad = lane >> 4;
  f32x4 acc[4][4];
  #pragma unroll
  for (int i = 0; i < 4; ++i)
    #pragma unroll
    for (int j = 0; j < 4; ++j) acc[i][j] = (f32x4){0.f, 0.f, 0.f, 0.f};
  #pragma unroll
  for (int ks = 0; ks < 4; ++ks) {
    bf16x8 af[4], bx[4];
    #pragma unroll
    for (int ot = 0; ot < 4; ++ot)
      af[ot] = *(const bf16x8*)&Wfrag[((((mat*4 + ks)*8) + (wo >> 4) + ot)*64 + lane)*8];
    #pragma unroll
    for (int mt = 0; mt < 4; ++mt)
      bx[mt] = *(const bf16x8*)&X16[(m0 + wm + mt*16 + lrow)*128 + ks*32 + quad*8];
    #pragma unroll
    for (int mt = 0; mt < 4; ++mt)
      #pragma unroll
      for (int ot = 0; ot < 4; ++ot)
        acc[mt][ot] = __builtin_amdgcn_mfma_f32_16x16x32_bf16(af[ot], bx[mt], acc[mt][ot], 0, 0, 0);
  }
  #pragma unroll
  for (int ot = 0; ot < 4; ++ot) {
    const int ocol = wo + ot*16 + quad*4;
    const float4 b4 = *(const float4*)&biasQKV[mat*128 + ocol];
    #pragma unroll
    for (int mt = 0; mt < 4; ++mt) {
      const long m = m0 + wm + mt*16 + lrow;
      ushort4 r;
      r.x = f2bf(acc[mt][ot][0] + b4.x);
      r.y = f2bf(acc[mt][ot][1] + b4.y);
      r.z = f2bf(acc[mt][ot][2] + b4.z);
      r.w = f2bf(acc[mt][ot][3] + b4.w);
      *(ushort4*)&Out[(size_t)mat * matStride + m*128 + ocol] = r;
    }
  }
}

// ---------------------------------------------------------------------------
// Dst-centric attention, ONE WAVE PER NODE (4 nodes per 256-block), zero
// __syncthreads. Per-wave private LDS region; cross-lane hand-off ordered by
// the wave's in-order DS pipe + s_waitcnt lgkmcnt(0).
//   - lane roles: scores/softmax (h=l>>4, q=(l>>1)&7, kh=l&1, 4 keys each),
//                 AV (lane owns output cols 2l,2l+1; head = l>>4)
//   - Q fragment + dst raw scores cached in registers (dst K staged once)
//   - src K prefetched one edge ahead (single reg buf, reloaded post-stage);
//     src V double-buffered in regs (column pairs, coalesced row loads)
//   - dst-side AV hoisted out of the edge loop: accumulate per-edge dst probs
//     (wd[4]/lane), single AV vs dst V at the end.
//   - sKf: f32 K tile, 16B-unit XOR swizzle (u^=u>>2) -> conflict-free b128
//     score reads; sPr: probs [4][100] so the 4 heads hit distinct banks.
// ---------------------------------------------------------------------------
__global__ __launch_bounds__(256) void node_attn(
    const ushort* __restrict__ Q, const ushort* __restrict__ Ki,
    const ushort* __restrict__ Vi, const ushort* __restrict__ Kj,
    const ushort* __restrict__ Vj, const int* __restrict__ off,
    const int* __restrict__ esrc, float* __restrict__ accum, int N)
{
  __shared__ float lds[4 * 1952];          // 30.5 KB: 4 independent wave regions
  const int t = threadIdx.x;
  const int wv = t >> 6, l = t & 63;
  const int n = blockIdx.x * 4 + wv;
  if (n >= N) return;
  const int e0 = off[n], deg = off[n + 1] - e0;
  if (deg == 0) return;                    // gemm_final masks via cnt==0

  float* R    = &lds[wv * 1952];
  float* sKf  = R;                         // [8 rows][128] f32, unit-swizzled
  float* sPr  = R + 1024;                  // [4 heads][100] probs (k*12+q)
  ushort* sVd = (ushort*)(R + 1424);       // [8][128] bf16 dst V (linear)

  const int hs = l >> 4, qs = (l >> 1) & 7, kh = l & 1;   // score/softmax role
  const int hA = l >> 4;                                  // AV role (cols 2l,2l+1)

  // ---- Q fragment: Q[qs][hs*32 .. +31] in 8 float4 ----
  float4 qv[8];
  {
    const uint4* qp = (const uint4*)(Q + (size_t)n * NODE_F + qs * 128 + hs * 32);
    #pragma unroll
    for (int c = 0; c < 4; ++c) {
      uint4 w = qp[c];
      qv[2*c+0] = make_float4(blo(w.x), bhi(w.x), blo(w.y), bhi(w.y));
      qv[2*c+1] = make_float4(blo(w.z), bhi(w.z), blo(w.w), bhi(w.w));
    }
  }

  // ---- K staging: global chunk (l*16B, +1024B) -> swizzled f32 tile ----
  const int srow = l >> 4, sh = (l & 15) >> 2, sj2 = (l & 3) * 2;
  const int u0 = sh * 8 + sj2;
  const int so0 = ((u0 & 24) | ((u0 ^ (u0 >> 2)) & 7)) * 4;
  const int u1 = u0 + 1;
  const int so1 = ((u1 & 24) | ((u1 ^ (u1 >> 2)) & 7)) * 4;
  auto stageK = [&](uint4 c0, uint4 c1) {
    float* p0 = &sKf[srow * 128];
    *(float4*)&p0[so0] = make_float4(blo(c0.x), bhi(c0.x), blo(c0.y), bhi(c0.y));
    *(float4*)&p0[so1] = make_float4(blo(c0.z), bhi(c0.z), blo(c0.w), bhi(c0.w));
    float* p1 = &sKf[(srow + 4) * 128];
    *(float4*)&p1[so0] = make_float4(blo(c1.x), bhi(c1.x), blo(c1.y), bhi(c1.y));
    *(float4*)&p1[so1] = make_float4(blo(c1.z), bhi(c1.z), blo(c1.w), bhi(c1.w));
  };

  int swo[8];
  #pragma unroll
  for (int j = 0; j < 8; ++j) {
    const int u = hs * 8 + j;
    swo[j] = ((u & 24) | ((u ^ (u >> 2)) & 7)) * 4;
  }
  auto scores4 = [&](float sc[4]) {
    #pragma unroll
    for (int i = 0; i < 4; ++i) {
      const float* kp = &sKf[(kh * 4 + i) * 128];
      float a = 0.f;
      #pragma unroll
      for (int j = 0; j < 8; ++j) {
        float4 b = *(const float4*)&kp[swo[j]];
        a += qv[j].x*b.x + qv[j].y*b.y + qv[j].z*b.z + qv[j].w*b.w;
      }
      sc[i] = a;
    }
  };

  // ---- dst K -> raw scores (regs), dst V -> LDS ----
  float sd[4];
  {
    const uint4* kp = (const uint4*)(Ki + (size_t)n * NODE_F);
    uint4 c0 = kp[l], c1 = kp[l + 64];
    const uint4* vp = (const uint4*)(Vi + (size_t)n * NODE_F);
    uint4 v0 = vp[l], v1 = vp[l + 64];
    stageK(c0, c1);
    ((uint4*)sVd)[l]      = v0;
    ((uint4*)sVd)[l + 64] = v1;
    asm volatile("s_waitcnt lgkmcnt(0)" ::: "memory");
    scores4(sd);
    asm volatile("" ::: "memory");   // keep dst-score reads before first stage
  }

  float2 oacc[8];
  #pragma unroll
  for (int q = 0; q < 8; ++q) oacc[q] = make_float2(0.f, 0.f);
  float wd[4] = {0.f, 0.f, 0.f, 0.f};

  auto avK = [&](int k, unsigned w) {
    const float vx = blo(w), vy = bhi(w);
    const float* pp = &sPr[hA * 100 + k * 12];
    float4 p0 = *(const float4*)&pp[0];
    float4 p1 = *(const float4*)&pp[4];
    oacc[0].x += p0.x*vx; oacc[0].y += p0.x*vy;
    oacc[1].x += p0.y*vx; oacc[1].y += p0.y*vy;
    oacc[2].x += p0.z*vx; oacc[2].y += p0.z*vy;
    oacc[3].x += p0.w*vx; oacc[3].y += p0.w*vy;
    oacc[4].x += p1.x*vx; oacc[4].y += p1.x*vy;
    oacc[5].x += p1.y*vx; oacc[5].y += p1.y*vy;
    oacc[6].x += p1.z*vx; oacc[6].y += p1.z*vy;
    oacc[7].x += p1.w*vx; oacc[7].y += p1.w*vy;
  };
  auto avStep = [&](const unsigned (&v)[8]) {
    #pragma unroll
    for (int k = 0; k < 8; ++k) avK(k, v[k]);
  };

  const uint4* KJ = (const uint4*)Kj;
  auto loadV = [&](unsigned (&vbuf)[8], int s) {
    const unsigned* vp = (const unsigned*)(Vj + (size_t)s * NODE_F) + l;
    #pragma unroll
    for (int k = 0; k < 8; ++k) vbuf[k] = vp[k * 64];
  };

  // ---- edge loop, one-iteration-ahead prefetch ----
  int src = esrc[e0];
  uint4 kb0 = KJ[(size_t)src * 128 + l];
  uint4 kb1 = KJ[(size_t)src * 128 + 64 + l];
  unsigned vA[8], vB[8];
  loadV(vA, src);
  int sn = (deg > 1) ? esrc[e0 + 1] : 0;

  for (int i = 0; i < deg; ++i) {
    stageK(kb0, kb1);
    if (i + 1 < deg) {
      kb0 = KJ[(size_t)sn * 128 + l];
      kb1 = KJ[(size_t)sn * 128 + 64 + l];
      if (i & 1) loadV(vA, sn); else loadV(vB, sn);
    }
    sn = (i + 2 < deg) ? esrc[e0 + i + 2] : 0;
    asm volatile("s_waitcnt lgkmcnt(0)" ::: "memory");

    float sc[4];
    scores4(sc);

    // full-wave softmax over 16 keys; lane pair (l, l^1) covers one (h,q) row
    float m = fmaxf(fmaxf(fmaxf(sc[0], sc[1]), fmaxf(sc[2], sc[3])),
                    fmaxf(fmaxf(sd[0], sd[1]), fmaxf(sd[2], sd[3])));
    m = fmaxf(m, __shfl_xor(m, 1));
    float es[4], ed[4], s = 0.f;
    #pragma unroll
    for (int k = 0; k < 4; ++k) {
      es[k] = __expf(sc[k] - m);
      ed[k] = __expf(sd[k] - m);
      s += es[k] + ed[k];
    }
    s += __shfl_xor(s, 1);
    const float inv = 1.f / s;
    #pragma unroll
    for (int k = 0; k < 4; ++k) {
      sPr[hs * 100 + (kh * 4 + k) * 12 + qs] = es[k] * inv;  // src probs
      wd[k] += ed[k] * inv;                                  // dst prob accum
    }
    asm volatile("s_waitcnt lgkmcnt(0)" ::: "memory");

    if (i & 1) avStep(vB); else avStep(vA);
  }

  // ---- hoisted dst-side AV: probs = accumulated wd, V = dst V ----
  asm volatile("s_waitcnt lgkmcnt(0)" ::: "memory");
  #pragma unroll
  for (int k = 0; k < 4; ++k)
    sPr[hs * 100 + (kh * 4 + k) * 12 + qs] = wd[k];
  asm volatile("s_waitcnt lgkmcnt(0)" ::: "memory");
  #pragma unroll
  for (int k = 0; k < 8; ++k)
    avK(k, *(const unsigned*)&sVd[k * 128 + 2 * l]);

  float* op = accum + (size_t)n * NODE_F + 2 * l;
  #pragma unroll
  for (int q = 0; q < 8; ++q) *(float2*)&op[q * 128] = oacc[q];
}

// ---------------------------------------------------------------------------
// Finalize (fp32): out = alpha * [cnt>0 ? (accum/cnt) @ WoT + bo : 0] (+= opt)
// ---------------------------------------------------------------------------
__global__ __launch_bounds__(256) void gemm_final(
    const float* __restrict__ Xacc, const int* __restrict__ cnt,
    const float* __restrict__ Wt, const float* __restrict__ bias,
    float* __restrict__ out, float alpha, int addTo, int M)
{
  __shared__ float xs[32][68];
  __shared__ float wsm[32][68];
  const int m0 = blockIdx.x * 64;
  const int oc0 = blockIdx.y * 64;
  const int t = threadIdx.x;
  const int tx = t & 15, ty = t >> 4;
  const int lr = t >> 3;
  const int lk = (t & 7) * 4;
  const int wk = t >> 3;
  const int wc = (t & 7) * 8;
  const int c0i = cnt[(m0 + lr) >> 3];
  const int c1i = cnt[(m0 + lr + 32) >> 3];
  const float inv0 = c0i > 0 ? 1.f / (float)c0i : 0.f;
  const float inv1 = c1i > 0 ? 1.f / (float)c1i : 0.f;
  float acc[4][4] = {};
  for (int kc = 0; kc < 128; kc += 32) {
    float4 x0 = *(const float4*)&Xacc[(long)(m0 + lr) * 128 + kc + lk];
    float4 x1 = *(const float4*)&Xacc[(long)(m0 + lr + 32) * 128 + kc + lk];
    const float* wr = &Wt[(long)(kc + wk) * 128 + oc0 + wc];
    float4 w0 = *(const float4*)&wr[0];
    float4 w1 = *(const float4*)&wr[4];
    __syncthreads();
    xs[lk+0][lr] = x0.x*inv0; xs[lk+1][lr] = x0.y*inv0; xs[lk+2][lr] = x0.z*inv0; xs[lk+3][lr] = x0.w*inv0;
    xs[lk+0][lr+32] = x1.x*inv1; xs[lk+1][lr+32] = x1.y*inv1; xs[lk+2][lr+32] = x1.z*inv1; xs[lk+3][lr+32] = x1.w*inv1;
    *(float4*)&wsm[wk][wc]     = w0;
    *(float4*)&wsm[wk][wc + 4] = w1;
    __syncthreads();
    #pragma unroll
    for (int kk = 0; kk < 32; ++kk) {
      float4 xv = *(const float4*)&xs[kk][ty * 4];
      float4 wv = *(const float4*)&wsm[kk][tx * 4];
      acc[0][0] += xv.x*wv.x; acc[0][1] += xv.x*wv.y; acc[0][2] += xv.x*wv.z; acc[0][3] += xv.x*wv.w;
      acc[1][0] += xv.y*wv.x; acc[1][1] += xv.y*wv.y; acc[1][2] += xv.y*wv.z; acc[1][3] += xv.y*wv.w;
      acc[2][0] += xv.z*wv.x; acc[2][1] += xv.z*wv.y; acc[2][2] += xv.z*wv.z; acc[2][3] += xv.z*wv.w;
      acc[3][0] += xv.w*wv.x; acc[3][1] += xv.w*wv.y; acc[3][2] += xv.w*wv.z; acc[3][3] += xv.w*wv.w;
    }
  }
  float b[4];
  #pragma unroll
  for (int j = 0; j < 4; ++j) b[j] = bias[oc0 + tx * 4 + j];
  #pragma unroll
  for (int i = 0; i < 4; ++i) {
    const int m = m0 + ty * 4 + i;
    const bool has = cnt[m >> 3] > 0;
    float4 v;
    v.x = has ? (acc[i][0] + b[0]) * alpha : 0.f;
    v.y = has ? (acc[i][1] + b[1]) * alpha : 0.f;
    v.z = has ? (acc[i][2] + b[2]) * alpha : 0.f;
    v.w = has ? (acc[i][3] + b[3]) * alpha : 0.f;
    float* op = &out[(long)m * 128 + oc0 + tx * 4];
    if (addTo) { float4 o = *(float4*)op; v.x += o.x; v.y += o.y; v.z += o.z; v.w += o.w; }
    *(float4*)op = v;
  }
}

// ---------------------------------------------------------------------------
extern "C" void kernel_launch(void* const* d_in, const int* in_sizes, int n_in,
                              void* d_out, int out_size, void* d_ws, size_t ws_size,
                              hipStream_t stream)
{
  const float* x_a = (const float*)d_in[0];
  const float* x_b = (const float*)d_in[1];
  const int* ei[3] = { (const int*)d_in[2], (const int*)d_in[3], (const int*)d_in[4] };
  RelW rw[3];
  for (int r = 0; r < 3; ++r) {
    const int base = 5 + r * 6;
    rw[r].Wb  = (const float*)d_in[base + 0];
    rw[r].bb  = (const float*)d_in[base + 1];
    rw[r].Win = (const float*)d_in[base + 2];
    rw[r].bin = (const float*)d_in[base + 3];
    rw[r].Wo  = (const float*)d_in[base + 4];
    rw[r].bo  = (const float*)d_in[base + 5];
  }
  const int N = in_sizes[0] / NODE_F;   // 20000
  const int E = in_sizes[2] / 2;        // 100000
  const int M = N * 8;                  // 160000 token rows (M%128==0)
  const size_t NF = (size_t)N * NODE_F;

  // ---- workspace carve-up (~370 MB) ----
  ushort* Qb    = (ushort*)d_ws;        // dst Q  (scale folded)   [NF] bf16
  ushort* Kib   = Qb  + NF;             // dst K                   (Q,Ki,Vi contiguous)
  ushort* Vib   = Kib + NF;
  ushort* Kjb   = Vib + NF;             // src K (Wb composed)     (Kj,Vj contiguous)
  ushort* Vjb   = Kjb + NF;
  ushort* xa16  = Vjb + NF;
  ushort* xb16  = xa16 + NF;
  ushort* Wfrag = xb16 + NF;            // 3 * 5*16384 bf16
  float* accum  = (float*)(Wfrag + (size_t)3*5*16384);   // [NF] fp32
  float* WoT    = accum + NF;           // 3 * 16384
  float* biasQKV= WoT + (size_t)3*16384;// 3 * 640
  float* biasO  = biasQKV + 3*640;      // 3 * 128
  int* counts   = (int*)(biasO + 3*128);// 3 * N
  int* offb     = counts + 3*N;         // 3 * (N+1)
  int* fillb    = offb + 3*(N+1);       // 3 * N
  int* esrc     = fillb + 3*N;          // 3 * E

  float* outA = (float*)d_out;          // (r2 + r3) * 0.5
  float* outB = outA + NF;              // r1

  // ---- CSR build for all relations (independent of weights) ----
  hipMemsetAsync(counts, 0, (size_t)3 * N * sizeof(int), stream);
  hist_edges<<<dim3((E + 255) / 256, 3), 256, 0, stream>>>(ei[0], ei[1], ei[2], counts, E, N);
  scan_offsets<<<3, 1024, 0, stream>>>(counts, offb, fillb, N);
  scatter_edges<<<dim3((E + 255) / 256, 3), 256, 0, stream>>>(ei[0], ei[1], ei[2], fillb, esrc, E, N);

  conv_bf16<<<dim3(N, 2), 256, 0, stream>>>(x_a, x_b, xa16, xb16);
  prep_weights<<<dim3(128, 6, 3), 128, 0, stream>>>(rw[0], rw[1], rw[2], Wfrag, WoT, biasQKV, biasO);

  const ushort* srcX[3] = { xa16, xb16, xa16 };
  const ushort* dstX[3] = { xb16, xa16, xa16 };
  float* outP[3]        = { outB, outA, outA };
  const float alpha[3]  = { 1.0f, 0.5f, 0.5f };
  const int addTo[3]    = { 0, 0, 1 };

  for (int r = 0; r < 3; ++r) {
    const ushort* wf = Wfrag + (size_t)r * 5 * 16384;
    const float* bq = biasQKV + r * 640;
    // dst-side Q/Ki/Vi (mats 0..2)
    gemm_mfma<<<dim3(M / 128, 3), 256, 0, stream>>>(dstX[r], wf, bq, Qb, (long)NF);
    // src-side Kj/Vj (mats 3..4)
    gemm_mfma<<<dim3(M / 128, 2), 256, 0, stream>>>(srcX[r], wf + (size_t)3*16384, bq + 3*128, Kjb, (long)NF);
    node_attn<<<dim3((N + 3) / 4), 256, 0, stream>>>(Qb, Kib, Vib, Kjb, Vjb,
                                                     offb + (size_t)r*(N+1), esrc + (size_t)r*E,
                                                     accum, N);
    gemm_final<<<dim3(M / 64, 2), 256, 0, stream>>>(accum, counts + (size_t)r*N,
                                                    WoT + (size_t)r*16384, biasO + r*128,
                                                    outP[r], alpha[r], addTo[r], M);
  }
}

// Round 4
// 1399.715 us; speedup vs baseline: 1.2637x; 1.0757x over previous
//
#include <hip/hip_runtime.h>

// Shapes fixed by the reference: H=4, D=128, S=8, dh=32.
#define NODE_F 1024                     // 8*128 elems per node

typedef short bf16x8 __attribute__((ext_vector_type(8)));
typedef short bf16x4 __attribute__((ext_vector_type(4)));
typedef float f32x4  __attribute__((ext_vector_type(4)));
typedef unsigned int u32x2 __attribute__((ext_vector_type(2)));

__device__ inline ushort f2bf(float f) {
  union { float f; unsigned u; } v; v.f = f;
  unsigned r = v.u + 0x7FFFu + ((v.u >> 16) & 1u);   // RNE
  return (ushort)(r >> 16);
}
__device__ inline float bf2f(ushort u) {
  union { unsigned u; float f; } v; v.u = ((unsigned)u) << 16;
  return v.f;
}

struct RelW { const float *Win, *bin, *Wb, *bb, *Wo, *bo; };

// ---------------------------------------------------------------------------
// Weight prep. Mats 0..4 (Q,Ki,Vi,KB,VB; Wb composed into KB/VB; 1/sqrt(dh)
// folded into Q) stored as bf16 in EXACT mfma_16x16x32 A-operand fragment
// order. Mat 5 (Wo) stays fp32 transposed [k][o] for fp32 finalize GEMM.
// ---------------------------------------------------------------------------
__global__ __launch_bounds__(128) void prep_weights(RelW r0, RelW r1, RelW r2,
    ushort* __restrict__ Wfrag, float* __restrict__ WoT,
    float* __restrict__ biasQKV, float* __restrict__ biasO)
{
  const int rel = blockIdx.z;
  RelW R = (rel == 0) ? r0 : (rel == 1 ? r1 : r2);
  const int o = blockIdx.x, m = blockIdx.y, k = threadIdx.x;
  const float scale = 0.17677669529663687f;   // 1/sqrt(32)
  float val;
  if (m == 0)      val = R.Win[o*128 + k] * scale;
  else if (m == 1) val = R.Win[(128+o)*128 + k];
  else if (m == 2) val = R.Win[(256+o)*128 + k];
  else if (m == 5) val = R.Wo[o*128 + k];
  else {
    const float* wr = R.Win + (m == 3 ? (128+o)*128 : (256+o)*128);
    float acc = 0.f;
    for (int i = 0; i < 128; ++i) acc += wr[i] * R.Wb[i*128 + k];
    val = acc;
  }
  if (m < 5) {
    const int ks = k >> 5, quad = (k >> 3) & 3, j = k & 7;
    const int ot = o >> 4, lane = quad * 16 + (o & 15);
    Wfrag[(size_t)rel*5*16384 + ((((m*4 + ks)*8 + ot)*64 + lane)*8 + j)] = f2bf(val);
  } else {
    WoT[(size_t)rel*16384 + k*128 + o] = val;
  }
  if (k == 0) {
    float bv;
    if (m == 0)      bv = R.bin[o] * scale;
    else if (m == 1) bv = R.bin[128+o];
    else if (m == 2) bv = R.bin[256+o];
    else if (m == 5) bv = R.bo[o];
    else {
      const float* wr = R.Win + (m == 3 ? (128+o)*128 : (256+o)*128);
      float acc = (m == 3) ? R.bin[128+o] : R.bin[256+o];
      for (int i = 0; i < 128; ++i) acc += wr[i] * R.bb[i];
      bv = acc;
    }
    if (m < 5) biasQKV[rel*640 + m*128 + o] = bv;
    else       biasO[rel*128 + o] = bv;
  }
}

// fp32 -> bf16 copies of x_a / x_b
__global__ __launch_bounds__(256) void conv_bf16(const float* __restrict__ xa,
    const float* __restrict__ xb, ushort* __restrict__ oa, ushort* __restrict__ ob)
{
  const float* x = blockIdx.y ? xb : xa;
  ushort* o = blockIdx.y ? ob : oa;
  const long i = ((long)blockIdx.x * 256 + threadIdx.x) * 4;
  float4 v = *(const float4*)&x[i];
  ushort4 r; r.x = f2bf(v.x); r.y = f2bf(v.y); r.z = f2bf(v.z); r.w = f2bf(v.w);
  *(ushort4*)&o[i] = r;
}

// --------------------------- CSR build (per relation) -----------------------
__global__ __launch_bounds__(256) void hist_edges(
    const int* __restrict__ e1, const int* __restrict__ e2, const int* __restrict__ e3,
    int* __restrict__ counts, int E, int N)
{
  const int r = blockIdx.y;
  const int* ei = (r == 0) ? e1 : (r == 1) ? e2 : e3;
  const int e = blockIdx.x * 256 + threadIdx.x;
  if (e < E) atomicAdd(&counts[(size_t)r * N + ei[E + e]], 1);
}

__global__ __launch_bounds__(1024) void scan_offsets(
    const int* __restrict__ counts, int* __restrict__ off,
    int* __restrict__ fill, int N)
{
  const int r = blockIdx.x;
  const int* cnt = counts + (size_t)r * N;
  int* offr  = off  + (size_t)r * (N + 1);
  int* fillr = fill + (size_t)r * N;
  __shared__ int buf[1024];
  __shared__ int carry;
  const int t = threadIdx.x;
  if (t == 0) carry = 0;
  __syncthreads();
  for (int base = 0; base < N; base += 1024) {
    const int idx = base + t;
    int v = (idx < N) ? cnt[idx] : 0;
    buf[t] = v;
    __syncthreads();
    for (int s = 1; s < 1024; s <<= 1) {
      int add = (t >= s) ? buf[t - s] : 0;
      __syncthreads();
      buf[t] += add;
      __syncthreads();
    }
    const int incl = buf[t];
    const int c = carry;
    if (idx < N) { offr[idx] = c + incl - v; fillr[idx] = c + incl - v; }
    __syncthreads();
    if (t == 1023) carry = c + incl;
    __syncthreads();
  }
  if (t == 0) offr[N] = carry;
}

__global__ __launch_bounds__(256) void scatter_edges(
    const int* __restrict__ e1, const int* __restrict__ e2, const int* __restrict__ e3,
    int* __restrict__ fill, int* __restrict__ esrc, int E, int N)
{
  const int r = blockIdx.y;
  const int* ei = (r == 0) ? e1 : (r == 1) ? e2 : e3;
  const int e = blockIdx.x * 256 + threadIdx.x;
  if (e < E) {
    const int d = ei[E + e], s = ei[e];
    const int pos = atomicAdd(&fill[(size_t)r * N + d], 1);
    esrc[(size_t)r * E + pos] = s;
  }
}

// ---------------------------------------------------------------------------
// MFMA projection GEMM. Normal path (harness-proven) for Q/K mats.
// For the V mat (mat == vtMat): operands swapped -> D transposed (D col =
// B-index, row = A-index, proven mapping), stored per-node transposed:
//   VT[node][feat 0..127][s 0..7]  (s = token within node = attention key)
// Each quad's 4 D-rows are 4 consecutive tokens inside ONE node -> ushort4.
// ---------------------------------------------------------------------------
__global__ __launch_bounds__(256) void gemm_mfma(
    const ushort* __restrict__ X16, const ushort* __restrict__ Wfrag,
    const float* __restrict__ biasQKV, ushort* __restrict__ Out, long matStride,
    int vtMat, ushort* __restrict__ VT)
{
  const int mat = blockIdx.y;
  const long m0 = (long)blockIdx.x * 128;
  const int t = threadIdx.x, wave = t >> 6, lane = t & 63;
  const int wm = (wave & 1) * 64, wo = (wave >> 1) * 64;
  const int lrow = lane & 15, quad = lane >> 4;
  f32x4 acc[4][4];
  #pragma unroll
  for (int i = 0; i < 4; ++i)
    #pragma unroll
    for (int j = 0; j < 4; ++j) acc[i][j] = (f32x4){0.f, 0.f, 0.f, 0.f};

  const bool swapped = (mat == vtMat);   // block-uniform

  #pragma unroll
  for (int ks = 0; ks < 4; ++ks) {
    bf16x8 af[4], bx[4];
    #pragma unroll
    for (int ot = 0; ot < 4; ++ot)
      af[ot] = *(const bf16x8*)&Wfrag[((((mat*4 + ks)*8) + (wo >> 4) + ot)*64 + lane)*8];
    #pragma unroll
    for (int mt = 0; mt < 4; ++mt)
      bx[mt] = *(const bf16x8*)&X16[(m0 + wm + mt*16 + lrow)*128 + ks*32 + quad*8];
    if (!swapped) {
      #pragma unroll
      for (int mt = 0; mt < 4; ++mt)
        #pragma unroll
        for (int ot = 0; ot < 4; ++ot)
          acc[mt][ot] = __builtin_amdgcn_mfma_f32_16x16x32_bf16(af[ot], bx[mt], acc[mt][ot], 0, 0, 0);
    } else {
      #pragma unroll
      for (int mt = 0; mt < 4; ++mt)
        #pragma unroll
        for (int ot = 0; ot < 4; ++ot)
          acc[mt][ot] = __builtin_amdgcn_mfma_f32_16x16x32_bf16(bx[mt], af[ot], acc[mt][ot], 0, 0, 0);
    }
  }

  if (!swapped) {
    #pragma unroll
    for (int ot = 0; ot < 4; ++ot) {
      const int ocol = wo + ot*16 + quad*4;
      const float4 b4 = *(const float4*)&biasQKV[mat*128 + ocol];
      #pragma unroll
      for (int mt = 0; mt < 4; ++mt) {
        const long m = m0 + wm + mt*16 + lrow;
        ushort4 r;
        r.x = f2bf(acc[mt][ot][0] + b4.x);
        r.y = f2bf(acc[mt][ot][1] + b4.y);
        r.z = f2bf(acc[mt][ot][2] + b4.z);
        r.w = f2bf(acc[mt][ot][3] + b4.w);
        *(ushort4*)&Out[(size_t)mat * matStride + m*128 + ocol] = r;
      }
    }
  } else {
    // D[row = token-within-tile = quad*4+reg][col = feat = lrow]
    #pragma unroll
    for (int ot = 0; ot < 4; ++ot) {
      const int feat = wo + ot*16 + lrow;
      const float bv = biasQKV[mat*128 + feat];
      #pragma unroll
      for (int mt = 0; mt < 4; ++mt) {
        const long tb = m0 + wm + mt*16;            // multiple of 16
        const long node = (tb >> 3) + (quad >> 1);
        const int  s0 = (quad & 1) * 4;
        ushort4 r;
        r.x = f2bf(acc[mt][ot][0] + bv);
        r.y = f2bf(acc[mt][ot][1] + bv);
        r.z = f2bf(acc[mt][ot][2] + bv);
        r.w = f2bf(acc[mt][ot][3] + bv);
        *(ushort4*)&VT[node*1024 + feat*8 + s0] = r;
      }
    }
  }
}

// ---------------------------------------------------------------------------
// Dst-centric attention, one wave per node, MFMA inner loop, ZERO LDS.
//   scores: mfma_16x16x32_bf16, A = K rows straight from global (lane = key
//           lr: rows lr<8 dst from Ki [loop-invariant regs], lr>=8 src from
//           Kj [exec-masked per-edge load]), B = Q-frag regs (q cols, zero-
//           padded q>=8) -> D[key][q]: lane q=l&15, keys 4*(l>>4)+reg.
//   softmax: in-reg, 2 shfl_xor; no max-sub (|s| << 1 for this input dist);
//           P packed as {bf16_hi, bf16_residual} -> fp32-accurate in one MFMA.
//   PV: A = V^T frags straight from global VT[node][feat][8] (quads 0-1 dst,
//       2-3 src masked), duplicated {v0..3,v0..3}; B = P. D[feat][q].
//   One-edge-ahead double-buffered prefetch (static A/B register names).
// ---------------------------------------------------------------------------
__global__ __launch_bounds__(256) void node_attn(
    const ushort* __restrict__ Q, const ushort* __restrict__ Ki,
    const ushort* __restrict__ VTi, const ushort* __restrict__ Kj,
    const ushort* __restrict__ VTj, const int* __restrict__ off,
    const int* __restrict__ esrc, float* __restrict__ accum, int N)
{
  const int t = threadIdx.x, wv = t >> 6, l = t & 63;
  const int n = blockIdx.x * 4 + wv;
  if (n >= N) return;
  const int e0 = off[n], deg = off[n + 1] - e0;
  if (deg == 0) return;                  // gemm_final masks via cnt==0

  const int lr = l & 15, lq = l >> 4;
  const int koff = (lr & 7) * 256 + lq * 16;   // K row byte offset within node
  const int voff = lr * 16 + (lq & 1) * 8;     // V^T byte offset within node

  // ---- Q B-frags (q = col = lr, zero-pad q>=8; row clamped in-bounds) ----
  bf16x8 qf[4];
  {
    const ushort* Qn = Q + (size_t)n * NODE_F;
    #pragma unroll
    for (int h = 0; h < 4; ++h) {
      bf16x8 v = *(const bf16x8*)&Qn[(lr & 7) * 128 + h * 32 + lq * 8];
      qf[h] = (lr < 8) ? v : (bf16x8)(short)0;
    }
  }

  const char* kD = (const char*)Ki  + (size_t)n * 2048 + koff;
  const char* vD = (const char*)VTi + (size_t)n * 2048 + voff;
  const char* KJ = (const char*)Kj;
  const char* VJ = (const char*)VTj;

  // dst halves fill both buffers once (persist under masked src loads)
  uint4 kA[4], kB[4]; u32x2 vA[8], vB[8];
  #pragma unroll
  for (int h = 0; h < 4; ++h) { kA[h] = *(const uint4*)(kD + h*64); kB[h] = kA[h]; }
  #pragma unroll
  for (int tt = 0; tt < 8; ++tt) { vA[tt] = *(const u32x2*)(vD + tt*256); vB[tt] = vA[tt]; }

  int srcN = (deg > 1) ? esrc[e0 + 1] : 0;
  {
    const int s0 = esrc[e0];
    if (lr >= 8) {
      const char* kb = KJ + (size_t)s0 * 2048 + koff;
      #pragma unroll
      for (int h = 0; h < 4; ++h) kA[h] = *(const uint4*)(kb + h*64);
    }
    if (lq >= 2) {
      const char* vb = VJ + (size_t)s0 * 2048 + voff;
      #pragma unroll
      for (int tt = 0; tt < 8; ++tt) vA[tt] = *(const u32x2*)(vb + tt*256);
    }
  }

  f32x4 acc[8];
  #pragma unroll
  for (int i = 0; i < 8; ++i) acc[i] = (f32x4){0.f, 0.f, 0.f, 0.f};

  auto body = [&](uint4 (&kf)[4], u32x2 (&vf)[8],
                  uint4 (&kn)[4], u32x2 (&vn)[8], int i) {
    if (i + 1 < deg) {       // prefetch next edge (src lanes only)
      if (lr >= 8) {
        const char* kb = KJ + (size_t)srcN * 2048 + koff;
        #pragma unroll
        for (int h = 0; h < 4; ++h) kn[h] = *(const uint4*)(kb + h*64);
      }
      if (lq >= 2) {
        const char* vb = VJ + (size_t)srcN * 2048 + voff;
        #pragma unroll
        for (int tt = 0; tt < 8; ++tt) vn[tt] = *(const u32x2*)(vb + tt*256);
      }
    }
    srcN = (i + 2 < deg) ? esrc[e0 + i + 2] : 0;

    // ---- scores: D[key][q], lane holds keys 4*lq+reg for q=lr ----
    f32x4 sc[4];
    #pragma unroll
    for (int h = 0; h < 4; ++h)
      sc[h] = __builtin_amdgcn_mfma_f32_16x16x32_bf16(
                __builtin_bit_cast(bf16x8, kf[h]), qf[h],
                (f32x4){0.f, 0.f, 0.f, 0.f}, 0, 0, 0);

    // ---- softmax over 16 keys per (h, q=lr); no max-sub (|s| << 1) ----
    bf16x8 pb[4];
    #pragma unroll
    for (int h = 0; h < 4; ++h) {
      float e0f = __expf(sc[h][0]), e1f = __expf(sc[h][1]);
      float e2f = __expf(sc[h][2]), e3f = __expf(sc[h][3]);
      float sum = (e0f + e1f) + (e2f + e3f);
      sum += __shfl_xor(sum, 16);
      sum += __shfl_xor(sum, 32);
      const float inv = 1.f / sum;
      float p0 = e0f*inv, p1 = e1f*inv, p2 = e2f*inv, p3 = e3f*inv;
      ushort h0 = f2bf(p0), h1 = f2bf(p1), h2 = f2bf(p2), h3 = f2bf(p3);
      bf16x8 b;
      b[0] = (short)h0; b[1] = (short)h1; b[2] = (short)h2; b[3] = (short)h3;
      b[4] = (short)f2bf(p0 - bf2f(h0));
      b[5] = (short)f2bf(p1 - bf2f(h1));
      b[6] = (short)f2bf(p2 - bf2f(h2));
      b[7] = (short)f2bf(p3 - bf2f(h3));
      pb[h] = b;
    }

    // ---- PV: A = dup(V^T frag), k-slot lq*8+j -> key lq*4+(j&3) ----
    #pragma unroll
    for (int tt = 0; tt < 8; ++tt) {
      bf16x4 v4 = __builtin_bit_cast(bf16x4, vf[tt]);
      bf16x8 a  = __builtin_shufflevector(v4, v4, 0,1,2,3, 0,1,2,3);
      acc[tt] = __builtin_amdgcn_mfma_f32_16x16x32_bf16(a, pb[tt >> 1], acc[tt], 0, 0, 0);
    }
  };

  for (int i = 0; i < deg; i += 2) {
    body(kA, vA, kB, vB, i);
    if (i + 1 < deg) body(kB, vB, kA, vA, i + 1);
  }

  // ---- store: D[feat][q]; lane (lr<8): q=lr, feats tt*16 + lq*4 .. +3 ----
  if (lr < 8) {
    float* op = accum + (size_t)n * NODE_F + lr * 128 + lq * 4;
    #pragma unroll
    for (int tt = 0; tt < 8; ++tt)
      *(f32x4*)&op[tt * 16] = acc[tt];
  }
}

// ---------------------------------------------------------------------------
// Finalize (fp32): out = alpha * [cnt>0 ? (accum/cnt) @ WoT + bo : 0] (+= opt)
// ---------------------------------------------------------------------------
__global__ __launch_bounds__(256) void gemm_final(
    const float* __restrict__ Xacc, const int* __restrict__ cnt,
    const float* __restrict__ Wt, const float* __restrict__ bias,
    float* __restrict__ out, float alpha, int addTo, int M)
{
  __shared__ float xs[32][68];
  __shared__ float wsm[32][68];
  const int m0 = blockIdx.x * 64;
  const int oc0 = blockIdx.y * 64;
  const int t = threadIdx.x;
  const int tx = t & 15, ty = t >> 4;
  const int lr = t >> 3;
  const int lk = (t & 7) * 4;
  const int wk = t >> 3;
  const int wc = (t & 7) * 8;
  const int c0i = cnt[(m0 + lr) >> 3];
  const int c1i = cnt[(m0 + lr + 32) >> 3];
  const float inv0 = c0i > 0 ? 1.f / (float)c0i : 0.f;
  const float inv1 = c1i > 0 ? 1.f / (float)c1i : 0.f;
  float acc[4][4] = {};
  for (int kc = 0; kc < 128; kc += 32) {
    float4 x0 = *(const float4*)&Xacc[(long)(m0 + lr) * 128 + kc + lk];
    float4 x1 = *(const float4*)&Xacc[(long)(m0 + lr + 32) * 128 + kc + lk];
    const float* wr = &Wt[(long)(kc + wk) * 128 + oc0 + wc];
    float4 w0 = *(const float4*)&wr[0];
    float4 w1 = *(const float4*)&wr[4];
    __syncthreads();
    xs[lk+0][lr] = x0.x*inv0; xs[lk+1][lr] = x0.y*inv0; xs[lk+2][lr] = x0.z*inv0; xs[lk+3][lr] = x0.w*inv0;
    xs[lk+0][lr+32] = x1.x*inv1; xs[lk+1][lr+32] = x1.y*inv1; xs[lk+2][lr+32] = x1.z*inv1; xs[lk+3][lr+32] = x1.w*inv1;
    *(float4*)&wsm[wk][wc]     = w0;
    *(float4*)&wsm[wk][wc + 4] = w1;
    __syncthreads();
    #pragma unroll
    for (int kk = 0; kk < 32; ++kk) {
      float4 xv = *(const float4*)&xs[kk][ty * 4];
      float4 wv = *(const float4*)&wsm[kk][tx * 4];
      acc[0][0] += xv.x*wv.x; acc[0][1] += xv.x*wv.y; acc[0][2] += xv.x*wv.z; acc[0][3] += xv.x*wv.w;
      acc[1][0] += xv.y*wv.x; acc[1][1] += xv.y*wv.y; acc[1][2] += xv.y*wv.z; acc[1][3] += xv.y*wv.w;
      acc[2][0] += xv.z*wv.x; acc[2][1] += xv.z*wv.y; acc[2][2] += xv.z*wv.z; acc[2][3] += xv.z*wv.w;
      acc[3][0] += xv.w*wv.x; acc[3][1] += xv.w*wv.y; acc[3][2] += xv.w*wv.z; acc[3][3] += xv.w*wv.w;
    }
  }
  float b[4];
  #pragma unroll
  for (int j = 0; j < 4; ++j) b[j] = bias[oc0 + tx * 4 + j];
  #pragma unroll
  for (int i = 0; i < 4; ++i) {
    const int m = m0 + ty * 4 + i;
    const bool has = cnt[m >> 3] > 0;
    float4 v;
    v.x = has ? (acc[i][0] + b[0]) * alpha : 0.f;
    v.y = has ? (acc[i][1] + b[1]) * alpha : 0.f;
    v.z = has ? (acc[i][2] + b[2]) * alpha : 0.f;
    v.w = has ? (acc[i][3] + b[3]) * alpha : 0.f;
    float* op = &out[(long)m * 128 + oc0 + tx * 4];
    if (addTo) { float4 o = *(float4*)op; v.x += o.x; v.y += o.y; v.z += o.z; v.w += o.w; }
    *(float4*)op = v;
  }
}

// ---------------------------------------------------------------------------
extern "C" void kernel_launch(void* const* d_in, const int* in_sizes, int n_in,
                              void* d_out, int out_size, void* d_ws, size_t ws_size,
                              hipStream_t stream)
{
  const float* x_a = (const float*)d_in[0];
  const float* x_b = (const float*)d_in[1];
  const int* ei[3] = { (const int*)d_in[2], (const int*)d_in[3], (const int*)d_in[4] };
  RelW rw[3];
  for (int r = 0; r < 3; ++r) {
    const int base = 5 + r * 6;
    rw[r].Wb  = (const float*)d_in[base + 0];
    rw[r].bb  = (const float*)d_in[base + 1];
    rw[r].Win = (const float*)d_in[base + 2];
    rw[r].bin = (const float*)d_in[base + 3];
    rw[r].Wo  = (const float*)d_in[base + 4];
    rw[r].bo  = (const float*)d_in[base + 5];
  }
  const int N = in_sizes[0] / NODE_F;   // 20000
  const int E = in_sizes[2] / 2;        // 100000
  const int M = N * 8;                  // 160000 token rows (M%128==0)
  const size_t NF = (size_t)N * NODE_F;

  // ---- workspace carve-up (~370 MB) ----
  ushort* Qb    = (ushort*)d_ws;        // dst Q  (scale folded)   [NF] bf16
  ushort* Kib   = Qb  + NF;             // dst K
  ushort* VTib  = Kib + NF;             // dst V^T [node][feat][8]
  ushort* Kjb   = VTib + NF;            // src K (Wb composed)
  ushort* VTjb  = Kjb + NF;             // src V^T (Wb composed)
  ushort* xa16  = VTjb + NF;
  ushort* xb16  = xa16 + NF;
  ushort* Wfrag = xb16 + NF;            // 3 * 5*16384 bf16
  float* accum  = (float*)(Wfrag + (size_t)3*5*16384);   // [NF] fp32
  float* WoT    = accum + NF;           // 3 * 16384
  float* biasQKV= WoT + (size_t)3*16384;// 3 * 640
  float* biasO  = biasQKV + 3*640;      // 3 * 128
  int* counts   = (int*)(biasO + 3*128);// 3 * N
  int* offb     = counts + 3*N;         // 3 * (N+1)
  int* fillb    = offb + 3*(N+1);       // 3 * N
  int* esrc     = fillb + 3*N;          // 3 * E

  float* outA = (float*)d_out;          // (r2 + r3) * 0.5
  float* outB = outA + NF;              // r1

  // ---- CSR build for all relations (independent of weights) ----
  hipMemsetAsync(counts, 0, (size_t)3 * N * sizeof(int), stream);
  hist_edges<<<dim3((E + 255) / 256, 3), 256, 0, stream>>>(ei[0], ei[1], ei[2], counts, E, N);
  scan_offsets<<<3, 1024, 0, stream>>>(counts, offb, fillb, N);
  scatter_edges<<<dim3((E + 255) / 256, 3), 256, 0, stream>>>(ei[0], ei[1], ei[2], fillb, esrc, E, N);

  conv_bf16<<<dim3(N, 2), 256, 0, stream>>>(x_a, x_b, xa16, xb16);
  prep_weights<<<dim3(128, 6, 3), 128, 0, stream>>>(rw[0], rw[1], rw[2], Wfrag, WoT, biasQKV, biasO);

  const ushort* srcX[3] = { xa16, xb16, xa16 };
  const ushort* dstX[3] = { xb16, xa16, xa16 };
  float* outP[3]        = { outB, outA, outA };
  const float alpha[3]  = { 1.0f, 0.5f, 0.5f };
  const int addTo[3]    = { 0, 0, 1 };

  for (int r = 0; r < 3; ++r) {
    const ushort* wf = Wfrag + (size_t)r * 5 * 16384;
    const float* bq = biasQKV + r * 640;
    // dst-side Q/Ki (normal) + Vi (transposed per-node -> VTib)
    gemm_mfma<<<dim3(M / 128, 3), 256, 0, stream>>>(dstX[r], wf, bq, Qb, (long)NF, 2, VTib);
    // src-side Kj (normal) + Vj (transposed per-node -> VTjb)
    gemm_mfma<<<dim3(M / 128, 2), 256, 0, stream>>>(srcX[r], wf + (size_t)3*16384, bq + 3*128,
                                                    Kjb, (long)NF, 1, VTjb);
    node_attn<<<dim3((N + 3) / 4), 256, 0, stream>>>(Qb, Kib, VTib, Kjb, VTjb,
                                                     offb + (size_t)r*(N+1), esrc + (size_t)r*E,
                                                     accum, N);
    gemm_final<<<dim3(M / 64, 2), 256, 0, stream>>>(accum, counts + (size_t)r*N,
                                                    WoT + (size_t)r*16384, biasO + r*128,
                                                    outP[r], alpha[r], addTo[r], M);
  }
}